// Round 1
// baseline (263.338 us; speedup 1.0000x reference)
//
#include <hip/hip_runtime.h>
#include <cmath>

constexpr int S = 160;
constexpr int BATCH = 4;
constexpr int ZSPLIT = 2;
constexpr int ROWS = S / ZSPLIT;               // 80 rows per block
constexpr int KC = S / 4;                      // 40 float4-chunks per row
constexpr int TPB = 256;
constexpr int LPR = 8;                         // lanes per row
constexpr int CPL = KC / LPR;                  // 5 float4 chunks per lane
constexpr int RPP = TPB / LPR;                 // 32 rows per pass
constexpr int PASSES = (ROWS + RPP - 1) / RPP; // 3 passes (32,32,16)

__device__ __forceinline__ float sigmoidf_(float x) {
  return 1.0f / (1.0f + expf(-x));
}

// wf[b][h][t] = (mask[b][t][h] != 0 && t != h) ? 1 : 0   (byte)
__global__ void prep_wf(const int* __restrict__ mask, unsigned char* __restrict__ wf) {
  int i = blockIdx.x * blockDim.x + threadIdx.x;
  if (i >= BATCH * S * S) return;
  int t = i % S;
  int bh = i / S;
  int h = bh % S;
  int b = bh / S;
  wf[i] = (mask[(b * S + t) * S + h] != 0 && t != h) ? 1 : 0;
}

// One block per (b, m, zhalf). Each 8-lane group owns one row h: 5 float4
// chunks per lane accumulated in registers, then shfl_xor reduce within the
// group. No LDS partial array, no post-stream barrier, deep load pipelining.
template <bool FIRST, bool LAST>
__global__ __launch_bounds__(TPB, 4) void mfvi_iter(
    const float* __restrict__ s_edge,   // [b][m][h]
    const float* __restrict__ s_sib,    // [b][m][h][t]
    const float* __restrict__ s_cop,
    const float* __restrict__ s_grd,
    const int* __restrict__ mask,       // [b][x][y]
    const unsigned char* __restrict__ wf,  // [b][h][t]
    const float* __restrict__ q1_in,    // [b][x][y] = q1[x,y,b]
    float* __restrict__ q1_out,
    float* __restrict__ outp) {         // [b][m][h][2]
  const int m = blockIdx.x;
  const int b = blockIdx.y;
  const int z = blockIdx.z;
  const int tid = threadIdx.x;

  __shared__ __align__(16) float colm[S];   // q1[t, m, b]
  __shared__ __align__(16) float rowm[S];   // q1[m, t, b]
  __shared__ float sef[ROWS];
  __shared__ float pmf[ROWS];

  const float* G = q1_in + (size_t)b * S * S;
  const size_t bm = (size_t)b * S + m;
  const int h0 = z * ROWS;

  if (tid < S) {
    if (!FIRST) {
      colm[tid] = G[tid * S + m];
      rowm[tid] = G[m * S + tid];
    }
    if (tid < ROWS) {
      sef[tid] = s_edge[bm * S + h0 + tid];
      pmf[tid] = (mask[bm * S + h0 + tid] != 0) ? 1.0f : 0.0f;
    }
  }
  __syncthreads();

  const size_t blk = (bm * S + h0) * (size_t)S;  // float offset of block region
  const float4* SS = (const float4*)(s_sib + blk);
  const float4* CC = (const float4*)(s_cop + blk);
  const float4* GG = (const float4*)(s_grd + blk);
  const float4* QQ = (const float4*)(G + h0 * S);
  const unsigned* WF = (const unsigned*)(wf + ((size_t)b * S + h0) * S);
  const int msel = m >> 2;
  const unsigned mclr = ~(255u << ((m & 3) * 8));

  const int g = tid >> 3;   // group index = row-within-pass
  const int j = tid & 7;    // lane within group

#pragma unroll
  for (int p = 0; p < PASSES; ++p) {
    const int r = p * RPP + g;
    if (r < ROWS) {
      const int rowbase = r * KC;
      float acc = 0.0f;
#pragma unroll
      for (int i = 0; i < CPL; ++i) {
        const int k = j + i * LPR;
        const int c = rowbase + k;
        unsigned wu = WF[c];
        float4 s = SS[c];
        float4 cv = CC[c];
        float4 gv = GG[c];
        if (k == msel) wu &= mclr;   // fold t != m
        float w0 = (float)(wu & 255u);
        float w1 = (float)((wu >> 8) & 255u);
        float w2 = (float)((wu >> 16) & 255u);
        float w3 = (float)(wu >> 24);
        if (FIRST) {  // q1 == 0.5 everywhere; 0.5 factor applied in epilogue
          float t0 = s.x + cv.x + gv.x;
          float t1 = s.y + cv.y + gv.y;
          float t2 = s.z + cv.z + gv.z;
          float t3 = s.w + cv.w + gv.w;
          acc = fmaf(w0, t0, fmaf(w1, t1, fmaf(w2, t2, fmaf(w3, t3, acc))));
        } else {
          float4 q = QQ[c];
          float4 cm = ((const float4*)colm)[k];
          float4 rm = ((const float4*)rowm)[k];
          float t0 = fmaf(q.x, s.x, fmaf(cm.x, cv.x, rm.x * gv.x));
          float t1 = fmaf(q.y, s.y, fmaf(cm.y, cv.y, rm.y * gv.y));
          float t2 = fmaf(q.z, s.z, fmaf(cm.z, cv.z, rm.z * gv.z));
          float t3 = fmaf(q.w, s.w, fmaf(cm.w, cv.w, rm.w * gv.w));
          acc = fmaf(w0, t0, fmaf(w1, t1, fmaf(w2, t2, fmaf(w3, t3, acc))));
        }
      }
      // reduce across the 8 lanes of the group (all within one wave)
      acc += __shfl_xor(acc, 1);
      acc += __shfl_xor(acc, 2);
      acc += __shfl_xor(acc, 4);
      if (j == 0) {
        const int h = h0 + r;
        const float qv = fmaf(pmf[r], FIRST ? 0.5f * acc : acc, sef[r]);
        if (!LAST) {
          q1_out[((size_t)b * S + h) * S + m] = sigmoidf_(qv);
        } else {
          float2 o;
          o.x = sigmoidf_(-qv);
          o.y = sigmoidf_(qv);
          ((float2*)outp)[bm * S + h] = o;
        }
      }
    }
  }
}

extern "C" void kernel_launch(void* const* d_in, const int* in_sizes, int n_in,
                              void* d_out, int out_size, void* d_ws, size_t ws_size,
                              hipStream_t stream) {
  const float* s_edge = (const float*)d_in[0];
  const float* s_sib = (const float*)d_in[1];
  const float* s_cop = (const float*)d_in[2];
  const float* s_grd = (const float*)d_in[3];
  const int* mask = (const int*)d_in[4];
  float* outp = (float*)d_out;

  const int qn = BATCH * S * S;
  float* q1A = (float*)d_ws;
  float* q1B = q1A + qn;
  unsigned char* wf = (unsigned char*)(q1B + qn);  // qn bytes

  prep_wf<<<(qn + 255) / 256, 256, 0, stream>>>(mask, wf);

  dim3 grid(S, BATCH, ZSPLIT);
  // iter 1: q1 == 0.5 (analytic) -> q1B
  mfvi_iter<true, false><<<grid, TPB, 0, stream>>>(
      s_edge, s_sib, s_cop, s_grd, mask, wf, q1A, q1B, nullptr);
  // iter 2: q1B -> q1A
  mfvi_iter<false, false><<<grid, TPB, 0, stream>>>(
      s_edge, s_sib, s_cop, s_grd, mask, wf, q1B, q1A, nullptr);
  // iter 3: q1A -> out (probabilities)
  mfvi_iter<false, true><<<grid, TPB, 0, stream>>>(
      s_edge, s_sib, s_cop, s_grd, mask, wf, q1A, nullptr, outp);
}

// Round 2
// 261.827 us; speedup vs baseline: 1.0058x; 1.0058x over previous
//
#include <hip/hip_runtime.h>
#include <cmath>

typedef _Float16 hf;
typedef hf hf4 __attribute__((ext_vector_type(4)));

constexpr int S = 160;
constexpr int BATCH = 4;
constexpr int KC = S / 4;                      // 40 float4/hf4 chunks per row
constexpr int TPB = 256;

// producer geometry (fp32 readers)
constexpr int ZSPLIT = 2;
constexpr int ROWS = S / ZSPLIT;               // 80 rows per block
constexpr int LPR = 8;                         // lanes per row
constexpr int CPL = KC / LPR;                  // 5 chunks per lane
constexpr int RPP = TPB / LPR;                 // 32 rows per pass
constexpr int PASSES = (ROWS + RPP - 1) / RPP; // 3

// consumer geometry (fp16 readers): chunk = 4 t's (8B), 40 chunks/row
constexpr int ZC = 5;
constexpr int CROWS = S / ZC;                  // 32 rows per block, single pass

__device__ __forceinline__ float sigmoidf_(float x) {
  return 1.0f / (1.0f + expf(-x));
}

// wf[b][h][t] = (mask[b][t][h] != 0 && t != h) ? 1 : 0   (byte)
__global__ void prep_wf(const int* __restrict__ mask, unsigned char* __restrict__ wf) {
  int i = blockIdx.x * blockDim.x + threadIdx.x;
  if (i >= BATCH * S * S) return;
  int t = i % S;
  int bh = i / S;
  int h = bh % S;
  int b = bh / S;
  wf[i] = (mask[(b * S + t) * S + h] != 0 && t != h) ? 1 : 0;
}

// Iter 1 (q1 == 0.5 analytic) + produce fully-masked fp16 copies of the three
// arrays (wf, t!=m, mask[h,m] all folded in) and q1 in both layouts.
__global__ __launch_bounds__(TPB, 4) void mfvi_first(
    const float* __restrict__ s_edge,   // [b][m][h]
    const float* __restrict__ s_sib,    // [b][m][h][t]
    const float* __restrict__ s_cop,
    const float* __restrict__ s_grd,
    const int* __restrict__ mask,       // [b][x][y]
    const unsigned char* __restrict__ wf,  // [b][h][t]
    hf* __restrict__ Aw, hf* __restrict__ Bw, hf* __restrict__ Cw,
    float* __restrict__ q1_out,         // [b][h][m]
    float* __restrict__ q1t_out) {      // [b][m][h]
  const int m = blockIdx.x;
  const int b = blockIdx.y;
  const int z = blockIdx.z;
  const int tid = threadIdx.x;

  __shared__ float sef[ROWS];
  __shared__ float pmf[ROWS];

  const size_t bm = (size_t)b * S + m;
  const int h0 = z * ROWS;

  if (tid < ROWS) {
    sef[tid] = s_edge[bm * S + h0 + tid];
    pmf[tid] = (mask[bm * S + h0 + tid] != 0) ? 1.0f : 0.0f;
  }
  __syncthreads();

  const size_t blk = (bm * S + h0) * (size_t)S;
  const float4* SS = (const float4*)(s_sib + blk);
  const float4* CC = (const float4*)(s_cop + blk);
  const float4* GG = (const float4*)(s_grd + blk);
  const unsigned* WF = (const unsigned*)(wf + ((size_t)b * S + h0) * S);
  hf* A16 = Aw + blk;
  hf* B16 = Bw + blk;
  hf* C16 = Cw + blk;
  const int msel = m >> 2;
  const unsigned mclr = ~(255u << ((m & 3) * 8));

  const int g = tid >> 3;
  const int j = tid & 7;

#pragma unroll
  for (int p = 0; p < PASSES; ++p) {
    const int r = p * RPP + g;
    if (r < ROWS) {
      const float pm = pmf[r];
      float acc = 0.0f;
#pragma unroll
      for (int i = 0; i < CPL; ++i) {
        const int k = j + i * LPR;
        const int c = r * KC + k;
        unsigned wu = WF[c];
        float4 s = SS[c];
        float4 cv = CC[c];
        float4 gv = GG[c];
        if (k == msel) wu &= mclr;   // fold t != m
        const float w0 = (float)(wu & 255u) * pm;
        const float w1 = (float)((wu >> 8) & 255u) * pm;
        const float w2 = (float)((wu >> 16) & 255u) * pm;
        const float w3 = (float)(wu >> 24) * pm;
        const float a0 = w0 * s.x, a1 = w1 * s.y, a2 = w2 * s.z, a3 = w3 * s.w;
        const float b0 = w0 * cv.x, b1 = w1 * cv.y, b2 = w2 * cv.z, b3 = w3 * cv.w;
        const float c0 = w0 * gv.x, c1 = w1 * gv.y, c2 = w2 * gv.z, c3 = w3 * gv.w;
        acc += ((a0 + b0 + c0) + (a1 + b1 + c1)) +
               ((a2 + b2 + c2) + (a3 + b3 + c3));
        hf4 av = {(hf)a0, (hf)a1, (hf)a2, (hf)a3};
        hf4 bv = {(hf)b0, (hf)b1, (hf)b2, (hf)b3};
        hf4 cw = {(hf)c0, (hf)c1, (hf)c2, (hf)c3};
        *(hf4*)(A16 + 4 * c) = av;
        *(hf4*)(B16 + 4 * c) = bv;
        *(hf4*)(C16 + 4 * c) = cw;
      }
      acc += __shfl_xor(acc, 1);
      acc += __shfl_xor(acc, 2);
      acc += __shfl_xor(acc, 4);
      if (j == 0) {
        const int h = h0 + r;
        const float qv = fmaf(0.5f, acc, sef[r]);   // pm folded into acc
        const float sg1 = sigmoidf_(qv);
        q1_out[((size_t)b * S + h) * S + m] = sg1;
        q1t_out[bm * S + h] = sg1;
      }
    }
  }
}

// Iters 2/3: pure triple-dot over pre-masked fp16 arrays. All masking folded.
template <bool LAST>
__global__ __launch_bounds__(TPB, 4) void mfvi_next(
    const float* __restrict__ s_edge,
    const hf* __restrict__ Aw, const hf* __restrict__ Bw, const hf* __restrict__ Cw,
    const float* __restrict__ q1_in,    // [b][h][m] layout [b][x][y]
    const float* __restrict__ q1t_in,   // [b][m][h]
    float* __restrict__ q1_out, float* __restrict__ q1t_out,
    float* __restrict__ outp) {         // [b][m][h][2]
  const int m = blockIdx.x;
  const int b = blockIdx.y;
  const int z = blockIdx.z;
  const int tid = threadIdx.x;

  __shared__ __align__(16) float colm[S];   // q1[t][m]
  __shared__ __align__(16) float rowm[S];   // q1[m][t]
  __shared__ float sef[CROWS];

  const size_t bm = (size_t)b * S + m;
  const int h0 = z * CROWS;

  if (tid < S) {
    colm[tid] = q1t_in[bm * S + tid];
    rowm[tid] = q1_in[bm * S + tid];     // q1[b][m][t] row is contiguous
    if (tid < CROWS) sef[tid] = s_edge[bm * S + h0 + tid];
  }
  __syncthreads();

  const size_t blk = (bm * S + h0) * (size_t)S;
  const hf* A16 = Aw + blk;
  const hf* B16 = Bw + blk;
  const hf* C16 = Cw + blk;
  const float4* QQ = (const float4*)(q1_in + (size_t)b * S * S + (size_t)h0 * S);

  const int r = tid >> 3;
  const int j = tid & 7;
  float acc = 0.0f;
#pragma unroll
  for (int i = 0; i < CPL; ++i) {
    const int k = j + i * LPR;
    const int c = r * KC + k;
    hf4 a = *(const hf4*)(A16 + 4 * c);
    hf4 bv = *(const hf4*)(B16 + 4 * c);
    hf4 g = *(const hf4*)(C16 + 4 * c);
    float4 q = QQ[c];
    float4 cm = ((const float4*)colm)[k];
    float4 rm = ((const float4*)rowm)[k];
    acc = fmaf(q.x, (float)a.x, fmaf(cm.x, (float)bv.x, fmaf(rm.x, (float)g.x, acc)));
    acc = fmaf(q.y, (float)a.y, fmaf(cm.y, (float)bv.y, fmaf(rm.y, (float)g.y, acc)));
    acc = fmaf(q.z, (float)a.z, fmaf(cm.z, (float)bv.z, fmaf(rm.z, (float)g.z, acc)));
    acc = fmaf(q.w, (float)a.w, fmaf(cm.w, (float)bv.w, fmaf(rm.w, (float)g.w, acc)));
  }
  acc += __shfl_xor(acc, 1);
  acc += __shfl_xor(acc, 2);
  acc += __shfl_xor(acc, 4);
  if (j == 0) {
    const int h = h0 + r;
    const float qv = sef[r] + acc;      // all masking already folded
    if (!LAST) {
      const float sg1 = sigmoidf_(qv);
      q1_out[((size_t)b * S + h) * S + m] = sg1;
      q1t_out[bm * S + h] = sg1;
    } else {
      float2 o;
      o.x = sigmoidf_(-qv);
      o.y = sigmoidf_(qv);
      ((float2*)outp)[bm * S + h] = o;
    }
  }
}

// ---------------- fallback (proven fp32 path, r1 kernel) ----------------
template <bool FIRST, bool LAST>
__global__ __launch_bounds__(TPB, 4) void mfvi_iter(
    const float* __restrict__ s_edge, const float* __restrict__ s_sib,
    const float* __restrict__ s_cop, const float* __restrict__ s_grd,
    const int* __restrict__ mask, const unsigned char* __restrict__ wf,
    const float* __restrict__ q1_in, float* __restrict__ q1_out,
    float* __restrict__ outp) {
  const int m = blockIdx.x;
  const int b = blockIdx.y;
  const int z = blockIdx.z;
  const int tid = threadIdx.x;

  __shared__ __align__(16) float colm[S];
  __shared__ __align__(16) float rowm[S];
  __shared__ float sef[ROWS];
  __shared__ float pmf[ROWS];

  const float* G = q1_in + (size_t)b * S * S;
  const size_t bm = (size_t)b * S + m;
  const int h0 = z * ROWS;

  if (tid < S) {
    if (!FIRST) {
      colm[tid] = G[tid * S + m];
      rowm[tid] = G[m * S + tid];
    }
    if (tid < ROWS) {
      sef[tid] = s_edge[bm * S + h0 + tid];
      pmf[tid] = (mask[bm * S + h0 + tid] != 0) ? 1.0f : 0.0f;
    }
  }
  __syncthreads();

  const size_t blk = (bm * S + h0) * (size_t)S;
  const float4* SS = (const float4*)(s_sib + blk);
  const float4* CC = (const float4*)(s_cop + blk);
  const float4* GG = (const float4*)(s_grd + blk);
  const float4* QQ = (const float4*)(G + h0 * S);
  const unsigned* WF = (const unsigned*)(wf + ((size_t)b * S + h0) * S);
  const int msel = m >> 2;
  const unsigned mclr = ~(255u << ((m & 3) * 8));

  const int g = tid >> 3;
  const int j = tid & 7;

#pragma unroll
  for (int p = 0; p < PASSES; ++p) {
    const int r = p * RPP + g;
    if (r < ROWS) {
      const int rowbase = r * KC;
      float acc = 0.0f;
#pragma unroll
      for (int i = 0; i < CPL; ++i) {
        const int k = j + i * LPR;
        const int c = rowbase + k;
        unsigned wu = WF[c];
        float4 s = SS[c];
        float4 cv = CC[c];
        float4 gv = GG[c];
        if (k == msel) wu &= mclr;
        float w0 = (float)(wu & 255u);
        float w1 = (float)((wu >> 8) & 255u);
        float w2 = (float)((wu >> 16) & 255u);
        float w3 = (float)(wu >> 24);
        if (FIRST) {
          float t0 = s.x + cv.x + gv.x;
          float t1 = s.y + cv.y + gv.y;
          float t2 = s.z + cv.z + gv.z;
          float t3 = s.w + cv.w + gv.w;
          acc = fmaf(w0, t0, fmaf(w1, t1, fmaf(w2, t2, fmaf(w3, t3, acc))));
        } else {
          float4 q = QQ[c];
          float4 cm = ((const float4*)colm)[k];
          float4 rm = ((const float4*)rowm)[k];
          float t0 = fmaf(q.x, s.x, fmaf(cm.x, cv.x, rm.x * gv.x));
          float t1 = fmaf(q.y, s.y, fmaf(cm.y, cv.y, rm.y * gv.y));
          float t2 = fmaf(q.z, s.z, fmaf(cm.z, cv.z, rm.z * gv.z));
          float t3 = fmaf(q.w, s.w, fmaf(cm.w, cv.w, rm.w * gv.w));
          acc = fmaf(w0, t0, fmaf(w1, t1, fmaf(w2, t2, fmaf(w3, t3, acc))));
        }
      }
      acc += __shfl_xor(acc, 1);
      acc += __shfl_xor(acc, 2);
      acc += __shfl_xor(acc, 4);
      if (j == 0) {
        const int h = h0 + r;
        const float qv = fmaf(pmf[r], FIRST ? 0.5f * acc : acc, sef[r]);
        if (!LAST) {
          q1_out[((size_t)b * S + h) * S + m] = sigmoidf_(qv);
        } else {
          float2 o;
          o.x = sigmoidf_(-qv);
          o.y = sigmoidf_(qv);
          ((float2*)outp)[bm * S + h] = o;
        }
      }
    }
  }
}

extern "C" void kernel_launch(void* const* d_in, const int* in_sizes, int n_in,
                              void* d_out, int out_size, void* d_ws, size_t ws_size,
                              hipStream_t stream) {
  const float* s_edge = (const float*)d_in[0];
  const float* s_sib = (const float*)d_in[1];
  const float* s_cop = (const float*)d_in[2];
  const float* s_grd = (const float*)d_in[3];
  const int* mask = (const int*)d_in[4];
  float* outp = (float*)d_out;

  const int qn = BATCH * S * S;                      // 102,400
  const size_t NS3 = (size_t)BATCH * S * S * S;      // 16,384,000 elements
  const size_t need = 3 * NS3 * sizeof(hf) + 4 * (size_t)qn * sizeof(float) + qn;

  if (ws_size >= need) {
    hf* Aw = (hf*)d_ws;
    hf* Bw = Aw + NS3;
    hf* Cw = Bw + NS3;
    float* q1B = (float*)(Cw + NS3);
    float* q1Bt = q1B + qn;
    float* q1A = q1Bt + qn;
    float* q1At = q1A + qn;
    unsigned char* wf = (unsigned char*)(q1At + qn);

    prep_wf<<<(qn + 255) / 256, 256, 0, stream>>>(mask, wf);

    dim3 gridP(S, BATCH, ZSPLIT);
    mfvi_first<<<gridP, TPB, 0, stream>>>(
        s_edge, s_sib, s_cop, s_grd, mask, wf, Aw, Bw, Cw, q1B, q1Bt);

    dim3 gridC(S, BATCH, ZC);
    mfvi_next<false><<<gridC, TPB, 0, stream>>>(
        s_edge, Aw, Bw, Cw, q1B, q1Bt, q1A, q1At, nullptr);
    mfvi_next<true><<<gridC, TPB, 0, stream>>>(
        s_edge, Aw, Bw, Cw, q1A, q1At, nullptr, nullptr, outp);
  } else {
    // fallback: proven fp32 path
    float* q1A = (float*)d_ws;
    float* q1B = q1A + qn;
    unsigned char* wf = (unsigned char*)(q1B + qn);

    prep_wf<<<(qn + 255) / 256, 256, 0, stream>>>(mask, wf);

    dim3 grid(S, BATCH, ZSPLIT);
    mfvi_iter<true, false><<<grid, TPB, 0, stream>>>(
        s_edge, s_sib, s_cop, s_grd, mask, wf, q1A, q1B, nullptr);
    mfvi_iter<false, false><<<grid, TPB, 0, stream>>>(
        s_edge, s_sib, s_cop, s_grd, mask, wf, q1B, q1A, nullptr);
    mfvi_iter<false, true><<<grid, TPB, 0, stream>>>(
        s_edge, s_sib, s_cop, s_grd, mask, wf, q1A, nullptr, outp);
  }
}